// Round 4
// baseline (43.931 us; speedup 1.0000x reference)
//
#include <hip/hip_runtime.h>

typedef __attribute__((ext_vector_type(8))) short bf16x8;   // 8 bf16 bit-patterns (4 VGPRs)
typedef __attribute__((ext_vector_type(4))) float f32x4;

// fp32 -> bf16 round-to-nearest-even (bit trick; inputs are finite randoms)
__device__ __forceinline__ short f2bf(float x) {
    unsigned u = __builtin_bit_cast(unsigned, x);
    u += 0x7fffu + ((u >> 16) & 1u);
    return (short)(u >> 16);
}

// Issue the 16 load instructions for one batch row (no waits here).
__device__ __forceinline__ void load_row(const float* __restrict__ bottom,
                                         const float* __restrict__ emb,
                                         int r, int lrow, int g,
                                         f32x4 (&w)[2][8]) {
    #pragma unroll
    for (int t = 0; t < 2; ++t) {
        const int f = 16 * t + lrow;
        const bool valid = (f < 27);
        const float* rowp = (f == 0)
            ? (bottom + (size_t)r * 128)
            : (emb + ((size_t)r * 26 + (valid ? (f - 1) : 0)) * 128);
        #pragma unroll
        for (int m = 0; m < 8; ++m) {
            if (valid) w[t][m] = *(const f32x4*)(rowp + m * 16 + g * 4);
            else       w[t][m] = f32x4{0.f, 0.f, 0.f, 0.f};  // pad rows never stored
        }
    }
}

// Convert -> MFMA Gram tiles -> scatter triu into LDS row -> 6 contiguous stores.
__device__ __forceinline__ void compute_store(const f32x4 (&w)[2][8],
                                              float* __restrict__ sr,
                                              float* __restrict__ orow,
                                              int lrow, int g, int lane) {
    // bf16 fragments; same fragment feeds both MFMA operand roles, so any
    // per-lane k-permutation cancels (Gram symmetry + shared layout).
    bf16x8 fr[2][4];
    #pragma unroll
    for (int t = 0; t < 2; ++t)
        #pragma unroll
        for (int n = 0; n < 32; ++n)
            fr[t][n >> 3][n & 7] = f2bf(w[t][n >> 2][n & 3]);

    f32x4 a00 = {0.f,0.f,0.f,0.f}, a01 = {0.f,0.f,0.f,0.f}, a11 = {0.f,0.f,0.f,0.f};
    #pragma unroll
    for (int s = 0; s < 4; ++s) {
        a00 = __builtin_amdgcn_mfma_f32_16x16x32_bf16(fr[0][s], fr[0][s], a00, 0, 0, 0);
        a01 = __builtin_amdgcn_mfma_f32_16x16x32_bf16(fr[0][s], fr[1][s], a01, 0, 0, 0);
        a11 = __builtin_amdgcn_mfma_f32_16x16x32_bf16(fr[1][s], fr[1][s], a11, 0, 0, 0);
    }

    // scatter triu values into LDS row: pairIdx(i,j) = i*(53-i)/2 + (j-i-1)
    // C/D map (m89-verified): col = lane&15, row = (lane>>4)*4 + reg
    const int row0 = g * 4;
    #pragma unroll
    for (int reg = 0; reg < 4; ++reg) {
        {   // tile (0,0): i,j in 0..15
            const int i = row0 + reg, j = lrow;
            if (i < j) sr[i * (53 - i) / 2 + (j - i - 1)] = a00[reg];
        }
        {   // tile (0,1): i in 0..15 (< j always), j in 16..31
            const int i = row0 + reg, j = 16 + lrow;
            if (j < 27) sr[i * (53 - i) / 2 + (j - i - 1)] = a01[reg];
        }
        {   // tile (1,1): i,j in 16..31
            const int i = 16 + row0 + reg, j = 16 + lrow;
            if (i < j && j < 27) sr[i * (53 - i) / 2 + (j - i - 1)] = a11[reg];
        }
    }
    // same-wave LDS producer/consumer, in-order DS pipe: no barrier needed

    // contiguous store: 6 dword instructions, 256B fully covered each
    #pragma unroll
    for (int i = 0; i < 6; ++i) {
        const int idx = lane + i * 64;
        if (idx < 351) orow[idx] = sr[idx];
    }
}

// Two batch rows per wave, software-pipelined: issue ALL 32 load instructions
// (rows A+B) before any use. While the wave converts/MFMAs/stores row A, row
// B's 16 KB stays in flight -> outstanding-read duty cycle ~100% (vs issue->
// drain->compute gaps in the 1-row version). VGPR ~180 -> 2 waves/SIMD; in-
// flight bytes/CU stays >=128 KB >> BW*latency (~9.2 KB) requirement.
__global__ __launch_bounds__(256) void fi_mfma_kernel(
    const float* __restrict__ bottom,   // [B, 128]
    const float* __restrict__ emb,      // [B, 26, 128]
    float* __restrict__ out,            // [B, 351]
    int B)
{
    __shared__ float srow[4][2][352];            // per-wave, per-row staging

    const int wave = threadIdx.x >> 6;
    const int lane = threadIdx.x & 63;
    const int rA = blockIdx.x * 8 + wave * 2;   // two consecutive batch rows
    const int rB = rA + 1;
    if (rA >= B) return;

    const int lrow = lane & 15;                 // feature-within-tile
    const int g    = lane >> 4;                 // lane group 0..3

    f32x4 wA[2][8], wB[2][8];
    load_row(bottom, emb, rA, lrow, g, wA);
    const bool haveB = (rB < B);
    load_row(bottom, emb, haveB ? rB : rA, lrow, g, wB);  // dup row A if tail

    compute_store(wA, srow[wave][0], out + (size_t)rA * 351, lrow, g, lane);
    if (haveB)
        compute_store(wB, srow[wave][1], out + (size_t)rB * 351, lrow, g, lane);
}

extern "C" void kernel_launch(void* const* d_in, const int* in_sizes, int n_in,
                              void* d_out, int out_size, void* d_ws, size_t ws_size,
                              hipStream_t stream) {
    const float* bottom = (const float*)d_in[0];   // (B, 128) fp32
    const float* emb    = (const float*)d_in[1];   // (B, 26, 128) fp32
    float* out          = (float*)d_out;           // (B, 351) fp32
    const int B = in_sizes[0] / 128;
    const int blocks = (B + 7) / 8;                // 4 waves x 2 rows per block
    fi_mfma_kernel<<<blocks, 256, 0, stream>>>(bottom, emb, out, B);
}